// Round 2
// baseline (493.083 us; speedup 1.0000x reference)
//
#include <hip/hip_runtime.h>

// M=K=N=8192. x:[M,K] fp32, weight:[N,K] fp32.
// y[m] = 0.75 * dot(x[m,:], colsum(weight))  -> out is [M,1] fp32 (8192 floats)

#define M_DIM 8192
#define K_DIM 8192
#define N_DIM 8192

#define CHUNKS 128            // row-chunks for colsum stage 1
#define ROWS   (N_DIM / CHUNKS)   // 64 rows per chunk

typedef float f32x4 __attribute__((ext_vector_type(4)));

// ---------------- Kernel 1a: column-sum partials (NO atomics) ----------------
// weight is [N, K] row-major. partial[c][k] = sum over chunk-c rows of w[., k].
// grid: (K/1024 = 8 column-groups, CHUNKS = 128 row-chunks), block = 256.
// Each thread owns one float4-column within its chunk, sums 64 rows with two
// independent accumulator chains, then does ONE plain float4 store.
// Previous version did 1M device-scope atomicAdds here (128-way collisions
// per address) -> atomic-serialization dominated. Plain stores remove that
// and also remove the need to zero wcs (no memset, no extra sync point).
__global__ __launch_bounds__(256) void colsum_partial_kernel(
    const float* __restrict__ w, f32x4* __restrict__ partial4) {
    const int col4 = blockIdx.x * 256 + threadIdx.x;   // float4-column index
    const int chunk = blockIdx.y;
    const int row0 = chunk * ROWS;
    const int stride4 = K_DIM / 4;
    const f32x4* __restrict__ p =
        (const f32x4*)w + (size_t)row0 * stride4 + col4;

    f32x4 a0 = (f32x4)0.f, a1 = (f32x4)0.f;
    #pragma unroll 8
    for (int r = 0; r < ROWS; r += 2) {
        f32x4 v0 = __builtin_nontemporal_load(p + (size_t)r * stride4);
        f32x4 v1 = __builtin_nontemporal_load(p + (size_t)(r + 1) * stride4);
        a0 += v0;
        a1 += v1;
    }
    a0 += a1;
    // partial is [CHUNKS][K] floats = [CHUNKS][2048] float4s (4 MB, L2-hot)
    partial4[(size_t)chunk * (K_DIM / 4) + col4] = a0;
}

// ---------------- Kernel 1b: fold partials -> wcs ----------------
// wcs[k] = sum_c partial[c][k]. 4 MB read (L2-resident), 32 KB write.
// grid: 8 blocks x 256 threads, one float4-column per thread.
__global__ __launch_bounds__(256) void colsum_reduce_kernel(
    const f32x4* __restrict__ partial4, f32x4* __restrict__ wcs4) {
    const int col4 = blockIdx.x * 256 + threadIdx.x;
    f32x4 a0 = (f32x4)0.f, a1 = (f32x4)0.f;
    #pragma unroll 8
    for (int c = 0; c < CHUNKS; c += 2) {
        a0 += partial4[(size_t)c * (K_DIM / 4) + col4];
        a1 += partial4[(size_t)(c + 1) * (K_DIM / 4) + col4];
    }
    wcs4[col4] = a0 + a1;
}

// ---------------- Kernel 2: per-row dot with wcs ----------------
// Wave-per-row: 2048 blocks x 4 waves = 8192 waves, one row of x each.
// No LDS, no __syncthreads -- pure wave-64 shuffle reduction.
// x has zero reuse -> nontemporal; wcs (32 KB) stays L2-hot via normal loads.
__global__ __launch_bounds__(256, 4) void rowdot_kernel(
    const float* __restrict__ x, const float* __restrict__ wcs,
    float* __restrict__ y) {
    const int wave = threadIdx.x >> 6;
    const int lane = threadIdx.x & 63;
    const int m = blockIdx.x * 4 + wave;
    const f32x4* __restrict__ x4 = (const f32x4*)(x + (size_t)m * K_DIM);
    const f32x4* __restrict__ w4 = (const f32x4*)wcs;

    f32x4 acc4 = (f32x4)0.f;
    #pragma unroll 8
    for (int j = 0; j < K_DIM / 4 / 64; ++j) {      // 32 iterations
        const int i = lane + 64 * j;
        f32x4 a = __builtin_nontemporal_load(x4 + i);
        f32x4 b = w4[i];
        acc4 += a * b;                               // 4 independent chains
    }
    float acc = acc4.x + acc4.y + acc4.z + acc4.w;
    #pragma unroll
    for (int off = 32; off > 0; off >>= 1)
        acc += __shfl_down(acc, off, 64);
    if (lane == 0) y[m] = 0.75f * acc;
}

extern "C" void kernel_launch(void* const* d_in, const int* in_sizes, int n_in,
                              void* d_out, int out_size, void* d_ws, size_t ws_size,
                              hipStream_t stream) {
    const float* x = (const float*)d_in[0];   // [M, K]
    const float* w = (const float*)d_in[1];   // [N, K]
    float* y = (float*)d_out;                 // [M] (== [M,1] flat)

    // ws layout: [0, 4 MB) = partial sums, [4 MB, 4 MB + 32 KB) = wcs.
    // Everything written before read -> no memset of poisoned ws needed.
    f32x4* partial4 = (f32x4*)d_ws;
    f32x4* wcs4 = (f32x4*)((char*)d_ws + (size_t)CHUNKS * K_DIM * sizeof(float));

    dim3 g1(K_DIM / 1024, CHUNKS);            // 8 x 128 = 1024 blocks
    colsum_partial_kernel<<<g1, 256, 0, stream>>>(w, partial4);

    colsum_reduce_kernel<<<K_DIM / 1024, 256, 0, stream>>>(partial4, wcs4);

    rowdot_kernel<<<M_DIM / 4, 256, 0, stream>>>(x, (const float*)wcs4, y);
}